// Round 3
// baseline (364.184 us; speedup 1.0000x reference)
//
#include <hip/hip_runtime.h>
#include <hip/hip_bf16.h>
#include <stdint.h>

typedef __bf16 bf16x8 __attribute__((ext_vector_type(8)));
typedef float f32x4 __attribute__((ext_vector_type(4)));
typedef float f32x16 __attribute__((ext_vector_type(16)));

#define NB_H 16
#define NB_KV 4
#define NB_HD 128
#define NB_B 2
#define NB_S 2048
#define NB_D 2048
#define NB_M (NB_B*NB_S)   /* 4096 */
#define NB_NQKV 3072
#define CAPF 50.0f
#define SCALEF 0.08838834764831845f

__device__ __forceinline__ ushort f2bf(float x){
  uint32_t u = __float_as_uint(x);
  u += 0x7fffu + ((u >> 16) & 1u);
  return (ushort)(u >> 16);
}
__device__ __forceinline__ float bf2f(ushort u){
  return __uint_as_float(((uint32_t)u) << 16);
}
__device__ __forceinline__ void gload_lds16(const void* g, void* l){
  __builtin_amdgcn_global_load_lds(
      (const __attribute__((address_space(1))) uint32_t*)g,
      (__attribute__((address_space(3))) uint32_t*)l, 16, 0, 0);
}

// ---------------- fused fp32 -> bf16 conversion (all 5 tensors, 1 launch) ----------------
// quad boundaries: hs 2097152 | Wq 1048576 | Wk 262144 | Wv 262144 | Wo 1048576
__global__ __launch_bounds__(256) void cvt_all(const float* __restrict__ hs,
                                               const float* __restrict__ wq,
                                               const float* __restrict__ wk,
                                               const float* __restrict__ wv,
                                               const float* __restrict__ wo,
                                               ushort* __restrict__ hsb,
                                               ushort* __restrict__ wqkv,
                                               ushort* __restrict__ wob){
  int q = blockIdx.x * blockDim.x + threadIdx.x;   // grid sized exactly
  const float* src; ushort* dst; int i;
  if (q < 2097152)      { src = hs; dst = hsb;            i = q; }
  else if (q < 3145728) { src = wq; dst = wqkv;           i = q - 2097152; }
  else if (q < 3407872) { src = wk; dst = wqkv + 4194304; i = q - 3145728; }
  else if (q < 3670016) { src = wv; dst = wqkv + 5242880; i = q - 3407872; }
  else                  { src = wo; dst = wob;            i = q - 3670016; }
  float4 v = ((const float4*)src)[i];
  ushort4 o;
  o.x = f2bf(v.x); o.y = f2bf(v.y); o.z = f2bf(v.z); o.w = f2bf(v.w);
  ((ushort4*)dst)[i] = o;
}

// ---------------- bf16 GEMM: C[M][N] = A[M][K] * B[N][K]^T (1D grid + XCD swizzle) ----------------
__global__ __launch_bounds__(256) void gemm_bt(const ushort* __restrict__ A,
                                               const ushort* __restrict__ Bw,
                                               ushort* __restrict__ Cb,
                                               float* __restrict__ Cf,
                                               int M, int N, int K, int nbx){
  int nwg = gridDim.x;
  int cpx = nwg >> 3;
  int wg = blockIdx.x;
  int swz = (wg & 7) * cpx + (wg >> 3);
  int bx = swz % nbx, by = swz / nbx;

  __shared__ ushort As[128 * 32];
  __shared__ ushort Bs[128 * 32];
  int tid = threadIdx.x;
  int w = tid >> 6, l = tid & 63;
  int lr = l & 15, lk = l >> 4;
  int row0 = by * 128, col0 = bx * 128;
  int wm = w >> 1, wn = w & 1;

  f32x4 acc[4][4];
#pragma unroll
  for (int mi = 0; mi < 4; ++mi)
#pragma unroll
    for (int nj = 0; nj < 4; ++nj)
      acc[mi][nj] = f32x4{0.f, 0.f, 0.f, 0.f};

  for (int k0 = 0; k0 < K; k0 += 32) {
#pragma unroll
    for (int c = 0; c < 2; ++c) {
      int off = w * 2048 + c * 1024 + l * 16;
      int r = off >> 6;
      int cb = off & 63;
      gload_lds16(A + (size_t)(row0 + r) * K + k0 + (cb >> 1), (char*)As + off);
      gload_lds16(Bw + (size_t)(col0 + r) * K + k0 + (cb >> 1), (char*)Bs + off);
    }
    __syncthreads();
    bf16x8 af[4], bfr[4];
#pragma unroll
    for (int mi = 0; mi < 4; ++mi)
      af[mi] = *(const bf16x8*)(As + (wm * 64 + mi * 16 + lr) * 32 + lk * 8);
#pragma unroll
    for (int nj = 0; nj < 4; ++nj)
      bfr[nj] = *(const bf16x8*)(Bs + (wn * 64 + nj * 16 + lr) * 32 + lk * 8);
    __builtin_amdgcn_s_setprio(1);
#pragma unroll
    for (int mi = 0; mi < 4; ++mi)
#pragma unroll
      for (int nj = 0; nj < 4; ++nj)
        acc[mi][nj] = __builtin_amdgcn_mfma_f32_16x16x32_bf16(af[mi], bfr[nj], acc[mi][nj], 0, 0, 0);
    __builtin_amdgcn_s_setprio(0);
    __syncthreads();
  }

#pragma unroll
  for (int mi = 0; mi < 4; ++mi)
#pragma unroll
    for (int nj = 0; nj < 4; ++nj)
#pragma unroll
      for (int i = 0; i < 4; ++i) {
        int r = row0 + wm * 64 + mi * 16 + lk * 4 + i;
        int c = col0 + wn * 64 + nj * 16 + lr;
        float v = acc[mi][nj][i];
        if (Cb) Cb[(size_t)r * N + c] = f2bf(v);
        else    Cf[(size_t)r * N + c] = v;
      }
}

// ---------------- RoPE in-place on Q (heads 0..15) and K (heads 16..19) ----------------
__global__ __launch_bounds__(256) void rope_kernel(ushort* __restrict__ qkv,
                                                   const float* __restrict__ cosb,
                                                   const float* __restrict__ sinb){
  int idx = blockIdx.x * blockDim.x + threadIdx.x;
  if (idx >= NB_M * 20 * 64) return;
  int row = idx / 1280;
  int rem = idx - row * 1280;
  int head = rem >> 6;
  int d = rem & 63;
  size_t base = (size_t)row * NB_NQKV + head * 128 + d;
  float a = bf2f(qkv[base]);
  float b = bf2f(qkv[base + 64]);
  float c = cosb[row * 128 + d];
  float s = sinb[row * 128 + d];
  qkv[base]      = f2bf(a * c - b * s);
  qkv[base + 64] = f2bf(b * c + a * s);
}

// ---------------- V transpose: vt[b][kv][d][s] ----------------
__global__ __launch_bounds__(256) void vtrans_kernel(const ushort* __restrict__ qkv,
                                                     ushort* __restrict__ vt){
  __shared__ ushort tile[64 * 136];
  int bid = blockIdx.x;
  int s0 = (bid & 31) * 64;
  int kvh = (bid >> 5) & 3;
  int b = bid >> 7;
  int tid = threadIdx.x;
#pragma unroll
  for (int i = 0; i < 4; ++i) {
    int g = tid + i * 256;
    int r = g >> 4, c = g & 15;
    *(uint4*)(tile + r * 136 + c * 8) =
        *(const uint4*)(qkv + (size_t)(b * NB_S + s0 + r) * NB_NQKV + 2560 + kvh * 128 + c * 8);
  }
  __syncthreads();
#pragma unroll
  for (int i = 0; i < 4; ++i) {
    int g = tid + i * 256;
    int dd = g >> 3, c = g & 7;
    union { ushort u[8]; uint4 v; } tmp;
#pragma unroll
    for (int j = 0; j < 8; ++j) tmp.u[j] = tile[(c * 8 + j) * 136 + dd];
    *(uint4*)(vt + ((size_t)(b * NB_KV + kvh) * NB_HD + dd) * NB_S + s0 + c * 8) = tmp.v;
  }
}

// ---------------- flash attention v3: 32x32 MFMA, no-max softmax, poly-tanh ----------------
// blk decode: XCD g = blk&7 -> (b,kvh); inner = blk>>3: j = inner>>2, h_lo = inner&3.
// 4 waves x 32 q-rows = 128 q/block; KVBLK=64; K/V double-buffered in swizzled LDS.
__global__ __launch_bounds__(256, 2) void attn_kernel(const ushort* __restrict__ qkv,
                                                      const ushort* __restrict__ vt,
                                                      ushort* __restrict__ obuf){
  __shared__ ushort lds[2][16384];   // per buf: K [64][128] (8192) | V^T [128][64] (8192)
  const int tid = threadIdx.x;
  const int w = tid >> 6, l = tid & 63;
  const int ql = l & 31, hi = l >> 5;
  const int blk = blockIdx.x;
  const int g = blk & 7;
  const int inner = blk >> 3;
  const int j = inner >> 2;
  const int h_lo = inner & 3;
  const int qt = (j < 8) ? (15 - j) : (j - 8);
  const int b = g >> 2, kvh = g & 3;
  const int h = kvh * 4 + h_lo;
  const int qbase = qt * 128 + w * 32;
  const int q = qbase + ql;
  const int nkt = 2 * (qt + 1);

  // staging addresses (pre-swizzled global source -> linear global_load_lds dest)
  size_t kidx[4], vidx[4];
#pragma unroll
  for (int i = 0; i < 4; ++i) {
    int s = i * 256 + tid;
    int kr = s >> 4, kc = s & 15;
    int kg = (kc & 8) | ((kc ^ kr) & 7);
    kidx[i] = (size_t)(b * NB_S + kr) * NB_NQKV + 2048 + kvh * 128 + kg * 8;
    int vr = s >> 3, vc = s & 7;
    int vg = (vc ^ vr) & 7;
    vidx[i] = ((size_t)(b * NB_KV + kvh) * NB_HD + vr) * NB_S + vg * 8;
  }

  // Q fragments (B-operand: lane holds q-col = ql, d = 16*dc + 8*hi + j)
  bf16x8 qf[8];
  {
    const ushort* qrow = qkv + (size_t)(b * NB_S + q) * NB_NQKV + h * 128 + hi * 8;
#pragma unroll
    for (int dc = 0; dc < 8; ++dc)
      qf[dc] = *(const bf16x8*)(qrow + dc * 16);
  }

  f32x16 acc[4];   // O^T accumulator: acc[dt] = 32d x 32q tile, col q = ql
#pragma unroll
  for (int dt = 0; dt < 4; ++dt)
#pragma unroll
    for (int r = 0; r < 16; ++r) acc[dt][r] = 0.f;
  float l_run = 0.f;

  // prologue stage
#pragma unroll
  for (int i = 0; i < 4; ++i)
    gload_lds16(qkv + kidx[i], (char*)lds[0] + (i * 256 + tid) * 16);
#pragma unroll
  for (int i = 0; i < 4; ++i)
    gload_lds16(vt + vidx[i], (char*)lds[0] + 16384 + (i * 256 + tid) * 16);
  __syncthreads();

  const float K1 = SCALEF / CAPF;                  // s -> x
  const float KW = SCALEF * 1.4426950408889634f;   // s -> w (= cap*log2e*x)

  int cur = 0;
  for (int kt = 0; kt < nkt; ++kt) {
    const int s0 = kt * 64;
    if (kt + 1 < nkt) {   // prefetch next tile into other buffer
      const size_t ks = (size_t)(kt + 1) * 64 * NB_NQKV;
      const int vs = (kt + 1) * 64;
#pragma unroll
      for (int i = 0; i < 4; ++i)
        gload_lds16(qkv + kidx[i] + ks, (char*)lds[cur ^ 1] + (i * 256 + tid) * 16);
#pragma unroll
      for (int i = 0; i < 4; ++i)
        gload_lds16(vt + vidx[i] + vs, (char*)lds[cur ^ 1] + 16384 + (i * 256 + tid) * 16);
    }
    const ushort* Kb = lds[cur];
    const ushort* Vb = lds[cur] + 8192;
    if (s0 <= qbase + 31) {   // wave-uniform skip of fully-masked tiles
      // S^T = mfma(K, Q): lane holds q = ql, k = (r&3)+8*(r>>2)+4*hi + 32t
      f32x16 st[2];
#pragma unroll
      for (int t = 0; t < 2; ++t) {
#pragma unroll
        for (int r = 0; r < 16; ++r) st[t][r] = 0.f;
        const int krow = t * 32 + ql;
        __builtin_amdgcn_s_setprio(1);
#pragma unroll
        for (int dc = 0; dc < 8; ++dc) {
          const int gd = dc * 2 + hi;
          const int g2 = (gd & 8) | ((gd ^ krow) & 7);
          bf16x8 kf = *(const bf16x8*)(Kb + krow * 128 + g2 * 8);
          st[t] = __builtin_amdgcn_mfma_f32_32x32x16_bf16(kf, qf[dc], st[t], 0, 0, 0);
        }
        __builtin_amdgcn_s_setprio(0);
      }
      // fused poly-tanh soft-cap + exp2 softmax (no max subtraction: capped <= 50)
      const bool full = (s0 + 63 <= qbase);        // wave-uniform
      const int qmb = q - s0 - 4 * hi;             // mask: koff <= qmb
      float p[2][16];
      float rs = 0.f;
#pragma unroll
      for (int t = 0; t < 2; ++t)
#pragma unroll
        for (int r = 0; r < 16; ++r) {
          float s = st[t][r];
          float x = s * K1;
          float x2 = x * x;
          float ww = s * KW;
          float t1 = fmaf(x2, 0.13333334f, -0.33333334f);   // tanh(x)/x - 1 over x2
          float y = fmaf(ww * x2, t1, ww);                  // cap*tanh(x)*log2e
          y = fminf(y, 72.134752f);                         // overflow guard
          if (!full) {
            const int koff = t * 32 + (r & 3) + 8 * (r >> 2);
            y = (koff <= qmb) ? y : -1e30f;
          }
          float pe = __builtin_amdgcn_exp2f(y);
          p[t][r] = pe;
          rs += pe;
        }
      rs += __shfl_xor(rs, 32);
      l_run += rs;
      // pack P to bf16 (hardware cvt_pk) and exchange 8 words across half-waves
      union { __bf16 hh16[32]; uint u[16]; } Pk;
#pragma unroll
      for (int t = 0; t < 2; ++t)
#pragma unroll
        for (int r = 0; r < 16; ++r)
          Pk.hh16[t * 16 + r] = (__bf16)p[t][r];
      uint rec[2][2][2];
#pragma unroll
      for (int t = 0; t < 2; ++t)
#pragma unroll
        for (int hh = 0; hh < 2; ++hh)
#pragma unroll
          for (int wb = 0; wb < 2; ++wb) {
            uint send = hi ? Pk.u[t * 8 + 4 * hh + wb] : Pk.u[t * 8 + 4 * hh + 2 + wb];
            rec[t][hh][wb] = __shfl_xor(send, 32);
          }
      // O^T += mfma(V^T, P^T)
#pragma unroll
      for (int c = 0; c < 4; ++c) {
        const int t = c >> 1, hh = c & 1;
        union { uint u[4]; bf16x8 v; } pf;
        pf.u[0] = hi ? rec[t][hh][0] : Pk.u[t * 8 + 4 * hh + 0];
        pf.u[1] = hi ? rec[t][hh][1] : Pk.u[t * 8 + 4 * hh + 1];
        pf.u[2] = hi ? Pk.u[t * 8 + 4 * hh + 2] : rec[t][hh][0];
        pf.u[3] = hi ? Pk.u[t * 8 + 4 * hh + 3] : rec[t][hh][1];
        __builtin_amdgcn_s_setprio(1);
#pragma unroll
        for (int dt = 0; dt < 4; ++dt) {
          const int vrow = dt * 32 + ql;
          const int gk = c * 2 + hi;
          const int g2 = (gk ^ vrow) & 7;
          bf16x8 vf = *(const bf16x8*)(Vb + vrow * 64 + g2 * 8);
          acc[dt] = __builtin_amdgcn_mfma_f32_32x32x16_bf16(vf, pf.v, acc[dt], 0, 0, 0);
        }
        __builtin_amdgcn_s_setprio(0);
      }
    }
    __syncthreads();
    cur ^= 1;
  }

  // epilogue: O^T -> LDS transpose (per-wave region) -> coalesced global store
  const float inv = __builtin_amdgcn_rcpf(l_run);
  ushort* reg = (ushort*)lds + (size_t)w * 4352;   // 32 rows x 136
#pragma unroll
  for (int dt = 0; dt < 4; ++dt)
#pragma unroll
    for (int gg = 0; gg < 4; ++gg) {
      ushort4 o;
      o.x = f2bf(acc[dt][4 * gg + 0] * inv);
      o.y = f2bf(acc[dt][4 * gg + 1] * inv);
      o.z = f2bf(acc[dt][4 * gg + 2] * inv);
      o.w = f2bf(acc[dt][4 * gg + 3] * inv);
      const int d0 = dt * 32 + gg * 8 + hi * 4;
      *(ushort4*)(reg + ql * 136 + d0) = o;
    }
  __syncthreads();
#pragma unroll
  for (int i = 0; i < 8; ++i) {
    const int qr = i * 4 + (l >> 4);
    const int c = l & 15;
    uint4 v = *(const uint4*)(reg + qr * 136 + c * 8);
    *(uint4*)(obuf + (size_t)(b * NB_S + qbase + qr) * NB_D + h * 128 + c * 8) = v;
  }
}

// ---------------- host launch ----------------
extern "C" void kernel_launch(void* const* d_in, const int* in_sizes, int n_in,
                              void* d_out, int out_size, void* d_ws, size_t ws_size,
                              hipStream_t stream) {
  const float* hs   = (const float*)d_in[0];
  const float* cosb = (const float*)d_in[1];
  const float* sinb = (const float*)d_in[2];
  const float* Wq   = (const float*)d_in[3];
  const float* Wk   = (const float*)d_in[4];
  const float* Wv   = (const float*)d_in[5];
  const float* Wo   = (const float*)d_in[6];
  float* out = (float*)d_out;
  char* ws = (char*)d_ws;

  ushort* hsb  = (ushort*)(ws + 0);
  ushort* wqkv = (ushort*)(ws + 16777216);
  ushort* wob  = (ushort*)(ws + 29360128);
  ushort* qkvb = (ushort*)(ws + 37748736);
  ushort* vtb  = (ushort*)(ws + 62914560);
  ushort* ob   = (ushort*)(ws + 67108864);

  cvt_all<<<18432, 256, 0, stream>>>(hs, Wq, Wk, Wv, Wo, hsb, wqkv, wob);

  gemm_bt<<<768, 256, 0, stream>>>(hsb, wqkv, qkvb, nullptr, NB_M, NB_NQKV, NB_D, 24);
  rope_kernel<<<(NB_M * 20 * 64 + 255) / 256, 256, 0, stream>>>(qkvb, cosb, sinb);
  vtrans_kernel<<<NB_B * NB_KV * (NB_S / 64), 256, 0, stream>>>(qkvb, vtb);

  attn_kernel<<<512, 256, 0, stream>>>(qkvb, vtb, ob);

  gemm_bt<<<512, 256, 0, stream>>>(ob, wob, nullptr, out, NB_M, NB_D, NB_D, 16);
}